// Round 8
// baseline (282.309 us; speedup 1.0000x reference)
//
#include <hip/hip_runtime.h>
#include <math.h>

// (B, F, NP, DIM, H, DH) = (4, 16, 196, 512, 8, 64)
#define B_   4
#define F_   16
#define NP_  196
#define DIM_ 512
#define H_   8
#define DH_  64
#define NTOT 3137            // 1 + F*NP
#define BH_  32              // B*H
#define MROWS 12548          // B*NTOT
#define QSZ_ ((size_t)BH_ * NTOT * DH_)   // elements per q/k/v buffer
#define KVPAD 224            // kv padded to 7 ksteps of 32
#define PSTRIDE 232          // P LDS row stride (u16): 16B-aligned, read-conflict-free
#define NCHUNK 13            // cls kv chunks of 256

typedef unsigned short u16;
typedef __attribute__((ext_vector_type(8))) short    bf16x8;
typedef __attribute__((ext_vector_type(8))) unsigned short u16x8;
typedef __attribute__((ext_vector_type(4))) unsigned short u16x4;
typedef __attribute__((ext_vector_type(4))) float    f32x4;

__device__ __forceinline__ u16 f2bf(float f) {
    unsigned int u = __float_as_uint(f);
    unsigned int r = (u + 0x7FFFu + ((u >> 16) & 1u)) >> 16;
    return (u16)r;
}
__device__ __forceinline__ float bf2f(u16 u) {
    return __uint_as_float(((unsigned int)u) << 16);
}

// ---------------------------------------------------------------------------
// convert x (fp32, MROWS x 512) -> bf16
// ---------------------------------------------------------------------------
__global__ __launch_bounds__(256) void convert_x_kernel(
    const float* __restrict__ x, u16* __restrict__ xbf)
{
    int idx = blockIdx.x * 256 + threadIdx.x;       // one float4 per thread
    float4 v = ((const float4*)x)[idx];
    u16x4 p = { f2bf(v.x), f2bf(v.y), f2bf(v.z), f2bf(v.w) };
    *(u16x4*)(&xbf[(size_t)idx * 4]) = p;
}

// ---------------------------------------------------------------------------
// transpose + bf16-convert: src (R x C fp32) -> dst (C x R bf16)
// ---------------------------------------------------------------------------
__global__ __launch_bounds__(256) void transpose_bf16_kernel(
    const float* __restrict__ src, u16* __restrict__ dst, int R, int C)
{
    __shared__ float t[32][33];
    const int tx = threadIdx.x & 31, ty = threadIdx.x >> 5;   // ty in 0..7
    const int c0 = blockIdx.x * 32, r0 = blockIdx.y * 32;
    #pragma unroll
    for (int i = 0; i < 4; ++i) {
        int r = ty + i * 8;
        t[r][tx] = src[(size_t)(r0 + r) * C + c0 + tx];
    }
    __syncthreads();
    #pragma unroll
    for (int i = 0; i < 4; ++i) {
        int cc = ty + i * 8;
        dst[(size_t)(c0 + cc) * R + r0 + tx] = f2bf(t[tx][cc]);
    }
}

// ---------------------------------------------------------------------------
// Fragment-direct bf16 MFMA GEMM (round-7 data-path change):
//   C = A(MROWS x 512) * BT^T   (BT is N x 512 bf16, K-contiguous)
// NO LDS, NO BARRIERS. Rounds 0-6 proved the LDS-staged barrier structure is
// pinned at ~80us (~6.4 B/cy/CU staging) regardless of buffering depth, vmcnt
// discipline, occupancy, iteration count, or tile shape -- the block-wide
// barrier convoy is the invariant. Here each lane loads its MFMA fragments
// DIRECTLY from global (16B gather, 16 cache lines per wave-load, 100% line
// utilization: lane l reads A[rowbase+(l&15)][k+(l>>4)*8..+7]). Waves are
// fully independent; the compiler can hoist loads across iterations without
// any barrier blocking code motion. Intra-block redundancy (A lines read by
// 2 waves, B by 2) is absorbed by L1; B (<=1.5MB) is L2-resident under the
// XCD swizzle (T1, bijective m204 -- FETCH 53->19.5MB verified round 2).
// 128x128 block tile, 4 waves 2x2, wave 64x64 via 4x4 mfma tiles, BK=64.
// MODE 0: qkv epilogue -> bf16 q (x0.125) / k / v [bh][n][64] + per-group V^T
// MODE 1: out epilogue (+bias, fp32 row-major)
// ---------------------------------------------------------------------------
template<int MODE>
__global__ __launch_bounds__(256) void gemm_bf16_mfma(
    const u16* __restrict__ A, const u16* __restrict__ BT,
    u16* __restrict__ Cq, u16* __restrict__ Ck, u16* __restrict__ Cv,
    u16* __restrict__ CvT, float* __restrict__ Cout, const float* __restrict__ bias)
{
    const int tid  = threadIdx.x;
    const int wave = tid >> 6, lane = tid & 63;
    const int wr = wave >> 1, wc = wave & 1;
    const int lm = lane & 15, lq = lane >> 4;

    // bijective XCD swizzle (m204): xcd = orig%8 gets contiguous wgid chunk
    constexpr int NX  = (MODE == 0) ? 12 : 4;
    constexpr int NWG = NX * 99;
    constexpr int SQ  = NWG / 8, SR = NWG % 8;
    const int orig = blockIdx.y * NX + blockIdx.x;
    const int xcd = orig & 7, loc = orig >> 3;
    const int wgid = (xcd < SR ? xcd * (SQ + 1) : SR * (SQ + 1) + (xcd - SR) * SQ) + loc;
    const int row0 = (wgid / NX) * 128;
    const int col0 = (wgid % NX) * 128;

    // per-lane fragment base pointers: fragment element j of lane l is
    // A[rowbase + (l&15)][k0 + (l>>4)*8 + j]  (same verified layout as the
    // LDS slab path of rounds 0-6, now addressed directly in global).
    const u16* Ap[4]; const u16* Bp[4];
    #pragma unroll
    for (int i = 0; i < 4; ++i) {
        int ar = row0 + (wr * 4 + i) * 16 + lm; if (ar >= MROWS) ar = MROWS - 1;
        int br = col0 + (wc * 4 + i) * 16 + lm;    // row of BT = output column
        Ap[i] = A  + (size_t)ar * 512 + lq * 8;
        Bp[i] = BT + (size_t)br * 512 + lq * 8;
    }

    f32x4 acc[4][4];
    #pragma unroll
    for (int i = 0; i < 4; ++i)
        #pragma unroll
        for (int j = 0; j < 4; ++j) acc[i][j] = (f32x4){0.f, 0.f, 0.f, 0.f};

    #pragma unroll
    for (int t = 0; t < 8; ++t) {               // BK=64 per step, K=512 total
        const int k0 = t * 64;
        bf16x8 a0[4], a1[4], b0[4], b1[4];
        #pragma unroll
        for (int i = 0; i < 4; ++i) {
            a0[i] = *(const bf16x8*)(Ap[i] + k0);
            a1[i] = *(const bf16x8*)(Ap[i] + k0 + 32);
            b0[i] = *(const bf16x8*)(Bp[i] + k0);
            b1[i] = *(const bf16x8*)(Bp[i] + k0 + 32);
        }
        #pragma unroll
        for (int mi = 0; mi < 4; ++mi)
            #pragma unroll
            for (int ni = 0; ni < 4; ++ni)
                acc[mi][ni] = __builtin_amdgcn_mfma_f32_16x16x32_bf16(
                    a0[mi], b0[ni], acc[mi][ni], 0, 0, 0);
        #pragma unroll
        for (int mi = 0; mi < 4; ++mi)
            #pragma unroll
            for (int ni = 0; ni < 4; ++ni)
                acc[mi][ni] = __builtin_amdgcn_mfma_f32_16x16x32_bf16(
                    a1[mi], b1[ni], acc[mi][ni], 0, 0, 0);
    }

    // epilogue: lane l, reg r -> row = sub16 + lq*4 + r, col = sub16 + lm
    if (MODE == 0) {
        const int t3 = col0 >> 9;          // uniform per block
        #pragma unroll
        for (int mi = 0; mi < 4; ++mi) {
            #pragma unroll
            for (int r = 0; r < 4; ++r) {
                int gr = row0 + wr * 64 + mi * 16 + lq * 4 + r;
                if (gr >= MROWS) continue;
                int b = gr / NTOT;
                int n = gr - b * NTOT;
                #pragma unroll
                for (int ni = 0; ni < 4; ++ni) {
                    int gc = col0 + wc * 64 + ni * 16 + lm;
                    int rem = gc & 511;
                    int h = rem >> 6, d = rem & 63;
                    int bh = b * H_ + h;
                    size_t tok = (size_t)bh * NTOT + n;
                    float v = acc[mi][ni][r];
                    if (t3 == 0) {
                        Cq[tok * 64 + d] = f2bf(v * 0.125f);
                    } else if (t3 == 1) {
                        Ck[tok * 64 + d] = f2bf(v);
                    } else {
                        u16 bv = f2bf(v);
                        Cv[tok * 64 + d] = bv;
                        if (n > 0) {                  // per-group V^T (cls filled later)
                            unsigned nn = (unsigned)(n - 1);
                            unsigned f = nn / 196u;
                            unsigned jj = nn - f * 196u + 1u;
                            CvT[((size_t)(bh * 16 + (int)f) * 64 + d) * KVPAD + jj] = bv;
                        }
                    }
                }
            }
        }
    } else {
        float bb[4];
        #pragma unroll
        for (int ni = 0; ni < 4; ++ni)
            bb[ni] = bias[col0 + wc * 64 + ni * 16 + lm];
        #pragma unroll
        for (int mi = 0; mi < 4; ++mi) {
            #pragma unroll
            for (int r = 0; r < 4; ++r) {
                int gr = row0 + wr * 64 + mi * 16 + lq * 4 + r;
                if (gr >= MROWS) continue;
                #pragma unroll
                for (int ni = 0; ni < 4; ++ni) {
                    int gc = col0 + wc * 64 + ni * 16 + lm;
                    Cout[(size_t)gr * 512 + gc] = acc[mi][ni][r] + bb[ni];
                }
            }
        }
    }
}

// ---------------------------------------------------------------------------
// replicate cls V row into position 0 of every group's V^T
// ---------------------------------------------------------------------------
__global__ __launch_bounds__(64) void vt_cls_fill_kernel(
    const u16* __restrict__ vb, u16* __restrict__ vT)
{
    const int bh = blockIdx.x, d = threadIdx.x;
    u16 val = vb[(size_t)bh * NTOT * 64 + d];
    #pragma unroll
    for (int f = 0; f < 16; ++f)
        vT[((size_t)(bh * 16 + f) * 64 + d) * KVPAD] = val;
}

// ---------------------------------------------------------------------------
// local attention, MFMA flash. One wave = one (bh, f, 16-q-row tile).
// ---------------------------------------------------------------------------
__global__ __launch_bounds__(256) void attn_mfma_kernel(
    const u16* __restrict__ qb, const u16* __restrict__ kb,
    const u16* __restrict__ vT, u16* __restrict__ attn)
{
    __shared__ alignas(16) u16 Pbuf[4 * 16 * PSTRIDE];

    const int tid  = threadIdx.x;
    const int wave = tid >> 6, lane = tid & 63;
    const int lm = lane & 15, lq = lane >> 4;
    const int task = blockIdx.x * 4 + wave;          // 0..6655
    const int mt = task % 13;
    const int gf = task / 13;
    const int f  = gf & 15;
    const int bh = gf >> 4;

    const int rq = min(mt * 16 + lm, 195);
    const u16* qrow = qb + ((size_t)bh * NTOT + (1 + f * NP_ + rq)) * 64;
    bf16x8 qf0 = *(const bf16x8*)(qrow + lq * 8);
    bf16x8 qf1 = *(const bf16x8*)(qrow + 32 + lq * 8);

    // S = Q K^T over 13 kv tiles of 16 (kv j = nt*16 + lm; j==0 is cls)
    f32x4 S[13];
    #pragma unroll
    for (int nt = 0; nt < 13; ++nt) {
        int rkc = min(nt * 16 + lm, 196);
        int nk = (rkc == 0) ? 0 : (1 + f * NP_ + rkc - 1);
        const u16* krow = kb + ((size_t)bh * NTOT + nk) * 64;
        bf16x8 kf0 = *(const bf16x8*)(krow + lq * 8);
        bf16x8 kf1 = *(const bf16x8*)(krow + 32 + lq * 8);
        f32x4 z = (f32x4){0.f, 0.f, 0.f, 0.f};
        z = __builtin_amdgcn_mfma_f32_16x16x32_bf16(qf0, kf0, z, 0, 0, 0);
        z = __builtin_amdgcn_mfma_f32_16x16x32_bf16(qf1, kf1, z, 0, 0, 0);
        S[nt] = z;
    }

    #pragma unroll
    for (int nt = 0; nt < 13; ++nt)
        if (nt * 16 + lm >= 197) {
            S[nt][0] = -INFINITY; S[nt][1] = -INFINITY;
            S[nt][2] = -INFINITY; S[nt][3] = -INFINITY;
        }

    // single-pass softmax; row = lq*4 + r, cols across the 16-lane group
    float invl[4];
    #pragma unroll
    for (int r = 0; r < 4; ++r) {
        float mx = -INFINITY;
        #pragma unroll
        for (int nt = 0; nt < 13; ++nt) mx = fmaxf(mx, S[nt][r]);
        mx = fmaxf(mx, __shfl_xor(mx, 1, 64));
        mx = fmaxf(mx, __shfl_xor(mx, 2, 64));
        mx = fmaxf(mx, __shfl_xor(mx, 4, 64));
        mx = fmaxf(mx, __shfl_xor(mx, 8, 64));
        float sum = 0.f;
        #pragma unroll
        for (int nt = 0; nt < 13; ++nt) {
            float p = __expf(S[nt][r] - mx);   // exp(-inf)=0 for masked cols
            S[nt][r] = p;
            sum += p;
        }
        sum += __shfl_xor(sum, 1, 64);
        sum += __shfl_xor(sum, 2, 64);
        sum += __shfl_xor(sum, 4, 64);
        sum += __shfl_xor(sum, 8, 64);
        invl[r] = 1.f / sum;
    }

    // P -> LDS (C-layout scatter), then re-read as A-fragments
    u16* P = Pbuf + wave * 16 * PSTRIDE;
    #pragma unroll
    for (int nt = 0; nt < 13; ++nt) {
        int col = nt * 16 + lm;
        #pragma unroll
        for (int r = 0; r < 4; ++r)
            P[(lq * 4 + r) * PSTRIDE + col] = f2bf(S[nt][r]);
    }
    {   // zero cols 208..223 (A-frag reads cover up to col 224)
        u16x4 z4 = {0, 0, 0, 0};
        *(u16x4*)(P + lm * PSTRIDE + 208 + lq * 4) = z4;
    }

    // O = P * V  (B operand from per-group V^T, kv-contiguous)
    f32x4 O[4];
    #pragma unroll
    for (int nd = 0; nd < 4; ++nd) O[nd] = (f32x4){0.f, 0.f, 0.f, 0.f};
    const u16* vbase = vT + (size_t)(bh * 16 + f) * 64 * KVPAD;
    #pragma unroll
    for (int ks = 0; ks < 7; ++ks) {
        bf16x8 pf = *(const bf16x8*)(P + lm * PSTRIDE + ks * 32 + lq * 8);
        #pragma unroll
        for (int nd = 0; nd < 4; ++nd) {
            bf16x8 vf = *(const bf16x8*)(vbase + (size_t)(nd * 16 + lm) * KVPAD + ks * 32 + lq * 8);
            O[nd] = __builtin_amdgcn_mfma_f32_16x16x32_bf16(pf, vf, O[nd], 0, 0, 0);
        }
    }

    const int b = bh >> 3, h = bh & 7;
    #pragma unroll
    for (int r = 0; r < 4; ++r) {
        int rql = mt * 16 + lq * 4 + r;
        if (rql >= 196) continue;
        int n = 1 + f * NP_ + rql;
        u16* dst = attn + ((size_t)b * NTOT + n) * 512 + h * 64;
        float s = invl[r];
        #pragma unroll
        for (int nd = 0; nd < 4; ++nd)
            dst[nd * 16 + lm] = f2bf(O[nd][r] * s);
    }
}

// ---------------------------------------------------------------------------
// cls attention, stage 1: grid (13 chunks, 32 bh), 256 threads.
// Phase A: thread = kv row; dot via 16B gather loads, 4 indep FMA chains.
// Phase B: thread = (quarter, d); P broadcast from LDS, V coalesced.
// Writes partial (m, l, o[64]) per (bh, chunk).
// ---------------------------------------------------------------------------
__global__ __launch_bounds__(256) void attn_cls_partial_kernel(
    const u16* __restrict__ qb, const u16* __restrict__ kb,
    const u16* __restrict__ vb, float* __restrict__ cls_m,
    float* __restrict__ cls_l, float* __restrict__ cls_o)
{
    __shared__ float qs[64];
    __shared__ float redm[4], redl[4];
    __shared__ float ps[256];
    __shared__ float so[4][64];

    const int c = blockIdx.x, bh = blockIdx.y;
    const int t = threadIdx.x;
    const int lane = t & 63, w = t >> 6;

    if (t < 64) qs[t] = bf2f(qb[(size_t)bh * NTOT * 64 + t]);   // q row 0, pre-scaled
    __syncthreads();

    // phase A: score for kv row j = c*256 + t
    const int j = c * 256 + t;
    const bool valid = (j < NTOT);
    const int jc = valid ? j : (NTOT - 1);
    const u16* krow = kb + ((size_t)bh * NTOT + jc) * 64;
    float s0 = 0.f, s1 = 0.f, s2 = 0.f, s3 = 0.f;
    #pragma unroll
    for (int i = 0; i < 8; ++i) {
        u16x8 k8 = *(const u16x8*)(krow + i * 8);
        const float* qp = qs + i * 8;
        s0 = fmaf(qp[0], bf2f(k8[0]), s0);
        s1 = fmaf(qp[1], bf2f(k8[1]), s1);
        s2 = fmaf(qp[2], bf2f(k8[2]), s2);
        s3 = fmaf(qp[3], bf2f(k8[3]), s3);
        s0 = fmaf(qp[4], bf2f(k8[4]), s0);
        s1 = fmaf(qp[5], bf2f(k8[5]), s1);
        s2 = fmaf(qp[6], bf2f(k8[6]), s2);
        s3 = fmaf(qp[7], bf2f(k8[7]), s3);
    }
    float s = (s0 + s1) + (s2 + s3);
    if (!valid) s = -INFINITY;

    // block max
    float mx = s;
    #pragma unroll
    for (int off = 1; off < 64; off <<= 1) mx = fmaxf(mx, __shfl_xor(mx, off, 64));
    if (lane == 0) redm[w] = mx;
    __syncthreads();
    mx = fmaxf(fmaxf(redm[0], redm[1]), fmaxf(redm[2], redm[3]));

    float pv = __expf(s - mx);                 // -inf -> 0
    float l = pv;
    #pragma unroll
    for (int off = 1; off < 64; off <<= 1) l += __shfl_xor(l, off, 64);
    if (lane == 0) redl[w] = l;
    ps[t] = pv;
    __syncthreads();
    l = redl[0] + redl[1] + redl[2] + redl[3];

    // phase B: o_d partial over this chunk's quarter
    const int d = lane, part = w;
    float o = 0.f;
    #pragma unroll 8
    for (int i = 0; i < 64; ++i) {
        int jj = c * 256 + part * 64 + i;
        int jjc = (jj < NTOT) ? jj : (NTOT - 1);
        o = fmaf(ps[part * 64 + i], bf2f(vb[((size_t)bh * NTOT + jjc) * 64 + d]), o);
    }
    so[part][d] = o;
    __syncthreads();
    if (t < 64) {
        float O = so[0][t] + so[1][t] + so[2][t] + so[3][t];
        int pi = bh * NCHUNK + c;
        cls_o[(size_t)pi * 64 + t] = O;
        if (t == 0) { cls_m[pi] = mx; cls_l[pi] = l; }
    }
}

// cls stage 2: merge 13 partials per bh, write bf16 row n=0.
__global__ __launch_bounds__(64) void attn_cls_merge_kernel(
    const float* __restrict__ cls_m, const float* __restrict__ cls_l,
    const float* __restrict__ cls_o, u16* __restrict__ attn)
{
    const int bh = blockIdx.x, lane = threadIdx.x;
    float M = -INFINITY;
    #pragma unroll
    for (int p = 0; p < NCHUNK; ++p) M = fmaxf(M, cls_m[bh * NCHUNK + p]);
    float L = 0.f, O = 0.f;
    #pragma unroll
    for (int p = 0; p < NCHUNK; ++p) {
        float al = __expf(cls_m[bh * NCHUNK + p] - M);
        L += cls_l[bh * NCHUNK + p] * al;
        O += cls_o[(size_t)(bh * NCHUNK + p) * 64 + lane] * al;
    }
    const int b = bh >> 3, h = bh & 7;
    attn[(size_t)b * NTOT * 512 + h * 64 + lane] = f2bf(O / L);
}

// ---------------------------------------------------------------------------
extern "C" void kernel_launch(void* const* d_in, const int* in_sizes, int n_in,
                              void* d_out, int out_size, void* d_ws, size_t ws_size,
                              hipStream_t stream) {
    const float* x    = (const float*)d_in[0];
    const float* wqkv = (const float*)d_in[1];
    const float* wout = (const float*)d_in[2];
    const float* bout = (const float*)d_in[3];

    u16* p = (u16*)d_ws;
    u16* xbf   = p;                    p += (size_t)MROWS * 512;  // reused as attn
    u16* attn  = xbf;                  // safe: xbf consumed by qkv gemm before attn writes
    u16* wqkvT = p;                    p += (size_t)1536 * 512;
    u16* woutT = p;                    p += (size_t)512 * 512;
    u16* qbuf  = p;                    p += QSZ_;
    u16* kbuf  = p;                    p += QSZ_;
    u16* vbuf  = p;                    p += QSZ_;
    u16* vT    = p;                    p += (size_t)BH_ * 16 * 64 * KVPAD;
    float* clsws = (float*)p;
    float* cls_m = clsws;                       // [32*13]
    float* cls_l = clsws + BH_ * NCHUNK;        // [32*13]
    float* cls_o = clsws + 2 * BH_ * NCHUNK;    // [32*13][64]
    float* outp  = (float*)d_out;

    // input conversions
    convert_x_kernel<<<6274, 256, 0, stream>>>(x, xbf);
    transpose_bf16_kernel<<<dim3(48, 16), 256, 0, stream>>>(wqkv, wqkvT, 512, 1536);
    transpose_bf16_kernel<<<dim3(16, 16), 256, 0, stream>>>(wout, woutT, 512, 512);
    // qkv = x @ W_qkv (fragment-direct MFMA), epilogue -> q/k/v + per-group V^T
    gemm_bf16_mfma<0><<<dim3(12, 99), 256, 0, stream>>>(
        xbf, wqkvT, qbuf, kbuf, vbuf, vT, nullptr, nullptr);
    vt_cls_fill_kernel<<<32, 64, 0, stream>>>(vbuf, vT);
    // attention
    attn_mfma_kernel<<<1664, 256, 0, stream>>>(qbuf, kbuf, vT, attn);
    attn_cls_partial_kernel<<<dim3(NCHUNK, 32), 256, 0, stream>>>(
        qbuf, kbuf, vbuf, cls_m, cls_l, cls_o);
    attn_cls_merge_kernel<<<32, 64, 0, stream>>>(cls_m, cls_l, cls_o, attn);
    // out = attn @ W_out + b_out (fragment-direct MFMA)
    gemm_bf16_mfma<1><<<dim3(4, 99), 256, 0, stream>>>(
        attn, woutT, nullptr, nullptr, nullptr, nullptr, outp, bout);
}

// Round 9
// 206.053 us; speedup vs baseline: 1.3701x; 1.3701x over previous
//
#include <hip/hip_runtime.h>
#include <math.h>

// (B, F, NP, DIM, H, DH) = (4, 16, 196, 512, 8, 64)
#define B_   4
#define F_   16
#define NP_  196
#define DIM_ 512
#define H_   8
#define DH_  64
#define NTOT 3137            // 1 + F*NP
#define BH_  32              // B*H
#define MROWS 12548          // B*NTOT
#define QSZ_ ((size_t)BH_ * NTOT * DH_)   // elements per q/k/v buffer
#define PSTRIDE 232          // P LDS row stride (u16): 16B-aligned, read-conflict-free
#define KSTRIDE 72           // K LDS row stride (u16): 2-way banks (free)
#define VSTRIDE 232          // V^T LDS row stride (u16): 2-way banks (free)
#define NCHUNK 13            // cls kv chunks of 256

typedef unsigned short u16;
typedef __attribute__((ext_vector_type(8))) short    bf16x8;
typedef __attribute__((ext_vector_type(8))) unsigned short u16x8;
typedef __attribute__((ext_vector_type(4))) unsigned short u16x4;
typedef __attribute__((ext_vector_type(4))) float    f32x4;

__device__ __forceinline__ u16 f2bf(float f) {
    unsigned int u = __float_as_uint(f);
    unsigned int r = (u + 0x7FFFu + ((u >> 16) & 1u)) >> 16;
    return (u16)r;
}
__device__ __forceinline__ float bf2f(u16 u) {
    return __uint_as_float(((unsigned int)u) << 16);
}

// async global->LDS, 16B per lane. LDS dest must be wave-uniform base + lane*16.
__device__ __forceinline__ void gl2lds16(const u16* g, u16* l) {
    __builtin_amdgcn_global_load_lds(
        (const __attribute__((address_space(1))) unsigned int*)(g),
        (__attribute__((address_space(3))) unsigned int*)(l),
        16, 0, 0);
}

// ---------------------------------------------------------------------------
// convert x (fp32, MROWS x 512) -> bf16
// ---------------------------------------------------------------------------
__global__ __launch_bounds__(256) void convert_x_kernel(
    const float* __restrict__ x, u16* __restrict__ xbf)
{
    int idx = blockIdx.x * 256 + threadIdx.x;       // one float4 per thread
    float4 v = ((const float4*)x)[idx];
    u16x4 p = { f2bf(v.x), f2bf(v.y), f2bf(v.z), f2bf(v.w) };
    *(u16x4*)(&xbf[(size_t)idx * 4]) = p;
}

// ---------------------------------------------------------------------------
// transpose + bf16-convert: src (R x C fp32) -> dst (C x R bf16)
// ---------------------------------------------------------------------------
__global__ __launch_bounds__(256) void transpose_bf16_kernel(
    const float* __restrict__ src, u16* __restrict__ dst, int R, int C)
{
    __shared__ float t[32][33];
    const int tx = threadIdx.x & 31, ty = threadIdx.x >> 5;   // ty in 0..7
    const int c0 = blockIdx.x * 32, r0 = blockIdx.y * 32;
    #pragma unroll
    for (int i = 0; i < 4; ++i) {
        int r = ty + i * 8;
        t[r][tx] = src[(size_t)(r0 + r) * C + c0 + tx];
    }
    __syncthreads();
    #pragma unroll
    for (int i = 0; i < 4; ++i) {
        int cc = ty + i * 8;
        dst[(size_t)(c0 + cc) * R + r0 + tx] = f2bf(t[tx][cc]);
    }
}

// ---------------------------------------------------------------------------
// bf16 MFMA GEMM (round-6 verified config: 80.2us MODE0):
//   C = A(MROWS x 512) * BT^T, 128x128 tile, BK=64, dbuf LDS, 4 waves 2x2.
// Rounds 0-8 established ~80us is this shape's floor across every staging
// structure (single/double/triple buffer, counted vmcnt, occupancy 10-32%,
// B-resident stream, fragment-direct no-LDS at 120us). Keep the best one.
// MODE 0: qkv epilogue -> bf16 q (x0.125) / k / v [bh][n][64]  (CvT scatter
//         REMOVED this round: V^T is now built in attn's LDS directly)
// MODE 1: out epilogue (+bias, fp32 row-major)
// ---------------------------------------------------------------------------
template<int MODE>
__global__ __launch_bounds__(256, 2) void gemm_bf16_mfma(
    const u16* __restrict__ A, const u16* __restrict__ BT,
    u16* __restrict__ Cq, u16* __restrict__ Ck, u16* __restrict__ Cv,
    float* __restrict__ Cout, const float* __restrict__ bias)
{
    __shared__ alignas(16) u16 Asm[2][16 * 512];   // 2 x 16 KB
    __shared__ alignas(16) u16 Bsm[2][16 * 512];   // 2 x 16 KB

    const int tid  = threadIdx.x;
    const int wave = tid >> 6, lane = tid & 63;
    const int wr = wave >> 1, wc = wave & 1;
    const int lm = lane & 15, lq = lane >> 4;

    // bijective XCD swizzle (m204)
    constexpr int NX  = (MODE == 0) ? 12 : 4;
    constexpr int NWG = NX * 99;
    constexpr int SQ  = NWG / 8, SR = NWG % 8;
    const int orig = blockIdx.y * NX + blockIdx.x;
    const int xcd = orig & 7, loc = orig >> 3;
    const int wgid = (xcd < SR ? xcd * (SQ + 1) : SR * (SQ + 1) + (xcd - SR) * SQ) + loc;
    const int row0 = (wgid / NX) * 128;
    const int col0 = (wgid % NX) * 128;

    // wave stages slabs wave*4 .. wave*4+3 of A and B (8 gl2lds/thread/K-step)
    const u16* ApS[4]; const u16* BpS[4]; int ldsOff[4];
    #pragma unroll
    for (int i = 0; i < 4; ++i) {
        int slab = wave * 4 + i;
        int s = slab >> 1, kh = slab & 1;
        int ar = row0 + s * 16 + lm; if (ar >= MROWS) ar = MROWS - 1;
        int br = col0 + s * 16 + lm;
        ApS[i]   = A  + (size_t)ar * 512 + kh * 32 + lq * 8;
        BpS[i]   = BT + (size_t)br * 512 + kh * 32 + lq * 8;
        ldsOff[i] = slab * 512 + lane * 8;
    }

    auto stage = [&](int T, int BUF) {
        const int kn = T * 64;
        #pragma unroll
        for (int i = 0; i < 4; ++i) {
            gl2lds16(ApS[i] + kn, &Asm[BUF][ldsOff[i]]);
            gl2lds16(BpS[i] + kn, &Bsm[BUF][ldsOff[i]]);
        }
    };

    f32x4 acc[4][4];
    #pragma unroll
    for (int i = 0; i < 4; ++i)
        #pragma unroll
        for (int j = 0; j < 4; ++j) acc[i][j] = (f32x4){0.f, 0.f, 0.f, 0.f};

    stage(0, 0);
    __syncthreads();

    #pragma unroll
    for (int t = 0; t < 8; ++t) {
        const int cur = t & 1;
        if (t + 1 < 8) stage(t + 1, cur ^ 1);
        #pragma unroll
        for (int kh = 0; kh < 2; ++kh) {
            bf16x8 af[4], bfr[4];
            #pragma unroll
            for (int mi = 0; mi < 4; ++mi)
                af[mi] = *(const bf16x8*)(&Asm[cur][((wr * 4 + mi) * 2 + kh) * 512 + lane * 8]);
            #pragma unroll
            for (int ni = 0; ni < 4; ++ni)
                bfr[ni] = *(const bf16x8*)(&Bsm[cur][((wc * 4 + ni) * 2 + kh) * 512 + lane * 8]);
            #pragma unroll
            for (int mi = 0; mi < 4; ++mi)
                #pragma unroll
                for (int ni = 0; ni < 4; ++ni)
                    acc[mi][ni] = __builtin_amdgcn_mfma_f32_16x16x32_bf16(
                        af[mi], bfr[ni], acc[mi][ni], 0, 0, 0);
        }
        __syncthreads();
    }

    // epilogue: lane l, reg r -> row = sub16 + lq*4 + r, col = sub16 + lm
    if (MODE == 0) {
        const int t3 = col0 >> 9;          // uniform per block
        #pragma unroll
        for (int mi = 0; mi < 4; ++mi) {
            #pragma unroll
            for (int r = 0; r < 4; ++r) {
                int gr = row0 + wr * 64 + mi * 16 + lq * 4 + r;
                if (gr >= MROWS) continue;
                int b = gr / NTOT;
                int n = gr - b * NTOT;
                #pragma unroll
                for (int ni = 0; ni < 4; ++ni) {
                    int gc = col0 + wc * 64 + ni * 16 + lm;
                    int rem = gc & 511;
                    int h = rem >> 6, d = rem & 63;
                    size_t tok = (size_t)(b * H_ + h) * NTOT + n;
                    float v = acc[mi][ni][r];
                    if (t3 == 0)      Cq[tok * 64 + d] = f2bf(v * 0.125f);
                    else if (t3 == 1) Ck[tok * 64 + d] = f2bf(v);
                    else              Cv[tok * 64 + d] = f2bf(v);
                }
            }
        }
    } else {
        float bb[4];
        #pragma unroll
        for (int ni = 0; ni < 4; ++ni)
            bb[ni] = bias[col0 + wc * 64 + ni * 16 + lm];
        #pragma unroll
        for (int mi = 0; mi < 4; ++mi) {
            #pragma unroll
            for (int r = 0; r < 4; ++r) {
                int gr = row0 + wr * 64 + mi * 16 + lq * 4 + r;
                if (gr >= MROWS) continue;
                #pragma unroll
                for (int ni = 0; ni < 4; ++ni) {
                    int gc = col0 + wc * 64 + ni * 16 + lm;
                    Cout[(size_t)gr * 512 + gc] = acc[mi][ni][r] + bb[ni];
                }
            }
        }
    }
}

// ---------------------------------------------------------------------------
// local attention, group-resident (round-9 restructure).
// One block per (bh,f) group: 512 blocks x 512 threads (8 waves).
// Stage once into LDS: K rows j=0..196 (cls + 196 patch rows, zero-padded to
// 208, row stride 72) and V^T (d=0..63 x kv=0..223, transposed from vbuf,
// zero-padded, row stride 232). Then 13 mt q-tiles split over 8 waves with
// the per-wave math VERBATIM from the verified kernel -- only kf/vf now read
// from LDS. Kills the 13x K/vT re-reads (373MB -> 28MB) and the 64-line
// vT gathers (448B lane stride) that made the old kernel gather-bound.
// LDS: K 29.9KB + V 29.7KB + P 59.4KB = 119KB -> 1 block/CU, 8 waves.
// ---------------------------------------------------------------------------
__global__ __launch_bounds__(512) void attn_group_kernel(
    const u16* __restrict__ qb, const u16* __restrict__ kb,
    const u16* __restrict__ vb, u16* __restrict__ attn)
{
    __shared__ alignas(16) u16 Ksm[208 * KSTRIDE];
    __shared__ alignas(16) u16 Vsm[64 * VSTRIDE];
    __shared__ alignas(16) u16 Pbuf[8 * 16 * PSTRIDE];

    const int tid  = threadIdx.x;
    const int wave = tid >> 6, lane = tid & 63;
    const int lm = lane & 15, lq = lane >> 4;
    const int gf = blockIdx.x;            // bh*16 + f
    const int f  = gf & 15;
    const int bh = gf >> 4;
    const int b = bh >> 3, h = bh & 7;
    const size_t kbase = (size_t)bh * NTOT;

    // ---- stage K: idx = (j, c); j = kv row 0..207, c = 16B chunk 0..7 ----
    for (int idx = tid; idx < 208 * 8; idx += 512) {
        int j = idx >> 3, c = idx & 7;
        u16x8 v8 = {0, 0, 0, 0, 0, 0, 0, 0};
        if (j < 197) {
            int n = (j == 0) ? 0 : (f * NP_ + j);      // 1 + f*196 + (j-1)
            v8 = *(const u16x8*)(kb + (kbase + n) * 64 + c * 8);
        }
        *(u16x8*)(&Ksm[j * KSTRIDE + c * 8]) = v8;
    }
    // ---- stage V transposed: idx = c*224 + j; c = d-chunk 0..7, j = kv ----
    for (int idx = tid; idx < 8 * 224; idx += 512) {
        int c = idx / 224, j = idx - c * 224;
        u16x8 v8 = {0, 0, 0, 0, 0, 0, 0, 0};
        if (j < 197) {
            int n = (j == 0) ? 0 : (f * NP_ + j);
            v8 = *(const u16x8*)(vb + (kbase + n) * 64 + c * 8);
        }
        #pragma unroll
        for (int e = 0; e < 8; ++e)
            Vsm[(c * 8 + e) * VSTRIDE + j] = v8[e];    // lanes: consec j -> 2-way banks
    }
    __syncthreads();

    u16* P = Pbuf + wave * 16 * PSTRIDE;
    {   // zero P cols 208..223 once per wave (A-frag reads cover up to 224)
        u16x4 z4 = {0, 0, 0, 0};
        *(u16x4*)(P + lm * PSTRIDE + 208 + lq * 4) = z4;
    }

    for (int mt = wave; mt < 13; mt += 8) {
        const int rq = min(mt * 16 + lm, 195);
        const u16* qrow = qb + (kbase + (1 + f * NP_ + rq)) * 64;
        bf16x8 qf0 = *(const bf16x8*)(qrow + lq * 8);
        bf16x8 qf1 = *(const bf16x8*)(qrow + 32 + lq * 8);

        // S = Q K^T over 13 kv tiles of 16 (kv j = nt*16 + lm; j==0 is cls)
        f32x4 S[13];
        #pragma unroll
        for (int nt = 0; nt < 13; ++nt) {
            const u16* krow = &Ksm[(nt * 16 + lm) * KSTRIDE];
            bf16x8 kf0 = *(const bf16x8*)(krow + lq * 8);
            bf16x8 kf1 = *(const bf16x8*)(krow + 32 + lq * 8);
            f32x4 z = (f32x4){0.f, 0.f, 0.f, 0.f};
            z = __builtin_amdgcn_mfma_f32_16x16x32_bf16(qf0, kf0, z, 0, 0, 0);
            z = __builtin_amdgcn_mfma_f32_16x16x32_bf16(qf1, kf1, z, 0, 0, 0);
            S[nt] = z;
        }

        #pragma unroll
        for (int nt = 0; nt < 13; ++nt)
            if (nt * 16 + lm >= 197) {
                S[nt][0] = -INFINITY; S[nt][1] = -INFINITY;
                S[nt][2] = -INFINITY; S[nt][3] = -INFINITY;
            }

        // single-pass softmax; row = lq*4 + r, cols across the 16-lane group
        float invl[4];
        #pragma unroll
        for (int r = 0; r < 4; ++r) {
            float mx = -INFINITY;
            #pragma unroll
            for (int nt = 0; nt < 13; ++nt) mx = fmaxf(mx, S[nt][r]);
            mx = fmaxf(mx, __shfl_xor(mx, 1, 64));
            mx = fmaxf(mx, __shfl_xor(mx, 2, 64));
            mx = fmaxf(mx, __shfl_xor(mx, 4, 64));
            mx = fmaxf(mx, __shfl_xor(mx, 8, 64));
            float sum = 0.f;
            #pragma unroll
            for (int nt = 0; nt < 13; ++nt) {
                float p = __expf(S[nt][r] - mx);   // exp(-inf)=0 for masked cols
                S[nt][r] = p;
                sum += p;
            }
            sum += __shfl_xor(sum, 1, 64);
            sum += __shfl_xor(sum, 2, 64);
            sum += __shfl_xor(sum, 4, 64);
            sum += __shfl_xor(sum, 8, 64);
            invl[r] = 1.f / sum;
        }

        // P -> LDS (C-layout scatter), then re-read as A-fragments
        #pragma unroll
        for (int nt = 0; nt < 13; ++nt) {
            int col = nt * 16 + lm;
            #pragma unroll
            for (int r = 0; r < 4; ++r)
                P[(lq * 4 + r) * PSTRIDE + col] = f2bf(S[nt][r]);
        }

        // O = P * V  (B operand from LDS V^T, kv-contiguous rows)
        f32x4 O[4];
        #pragma unroll
        for (int nd = 0; nd < 4; ++nd) O[nd] = (f32x4){0.f, 0.f, 0.f, 0.f};
        #pragma unroll
        for (int ks = 0; ks < 7; ++ks) {
            bf16x8 pf = *(const bf16x8*)(P + lm * PSTRIDE + ks * 32 + lq * 8);
            #pragma unroll
            for (int nd = 0; nd < 4; ++nd) {
                bf16x8 vf = *(const bf16x8*)(&Vsm[(nd * 16 + lm) * VSTRIDE + ks * 32 + lq * 8]);
                O[nd] = __builtin_amdgcn_mfma_f32_16x16x32_bf16(pf, vf, O[nd], 0, 0, 0);
            }
        }

        #pragma unroll
        for (int r = 0; r < 4; ++r) {
            int rql = mt * 16 + lq * 4 + r;
            if (rql >= 196) continue;
            int n = 1 + f * NP_ + rql;
            u16* dst = attn + ((size_t)b * NTOT + n) * 512 + h * 64;
            float s = invl[r];
            #pragma unroll
            for (int nd = 0; nd < 4; ++nd)
                dst[nd * 16 + lm] = f2bf(O[nd][r] * s);
        }
    }
}

// ---------------------------------------------------------------------------
// cls attention, stage 1: grid (13 chunks, 32 bh), 256 threads.
// ---------------------------------------------------------------------------
__global__ __launch_bounds__(256) void attn_cls_partial_kernel(
    const u16* __restrict__ qb, const u16* __restrict__ kb,
    const u16* __restrict__ vb, float* __restrict__ cls_m,
    float* __restrict__ cls_l, float* __restrict__ cls_o)
{
    __shared__ float qs[64];
    __shared__ float redm[4], redl[4];
    __shared__ float ps[256];
    __shared__ float so[4][64];

    const int c = blockIdx.x, bh = blockIdx.y;
    const int t = threadIdx.x;
    const int lane = t & 63, w = t >> 6;

    if (t < 64) qs[t] = bf2f(qb[(size_t)bh * NTOT * 64 + t]);   // q row 0, pre-scaled
    __syncthreads();

    // phase A: score for kv row j = c*256 + t
    const int j = c * 256 + t;
    const bool valid = (j < NTOT);
    const int jc = valid ? j : (NTOT - 1);
    const u16* krow = kb + ((size_t)bh * NTOT + jc) * 64;
    float s0 = 0.f, s1 = 0.f, s2 = 0.f, s3 = 0.f;
    #pragma unroll
    for (int i = 0; i < 8; ++i) {
        u16x8 k8 = *(const u16x8*)(krow + i * 8);
        const float* qp = qs + i * 8;
        s0 = fmaf(qp[0], bf2f(k8[0]), s0);
        s1 = fmaf(qp[1], bf2f(k8[1]), s1);
        s2 = fmaf(qp[2], bf2f(k8[2]), s2);
        s3 = fmaf(qp[3], bf2f(k8[3]), s3);
        s0 = fmaf(qp[4], bf2f(k8[4]), s0);
        s1 = fmaf(qp[5], bf2f(k8[5]), s1);
        s2 = fmaf(qp[6], bf2f(k8[6]), s2);
        s3 = fmaf(qp[7], bf2f(k8[7]), s3);
    }
    float s = (s0 + s1) + (s2 + s3);
    if (!valid) s = -INFINITY;

    // block max
    float mx = s;
    #pragma unroll
    for (int off = 1; off < 64; off <<= 1) mx = fmaxf(mx, __shfl_xor(mx, off, 64));
    if (lane == 0) redm[w] = mx;
    __syncthreads();
    mx = fmaxf(fmaxf(redm[0], redm[1]), fmaxf(redm[2], redm[3]));

    float pv = __expf(s - mx);                 // -inf -> 0
    float l = pv;
    #pragma unroll
    for (int off = 1; off < 64; off <<= 1) l += __shfl_xor(l, off, 64);
    if (lane == 0) redl[w] = l;
    ps[t] = pv;
    __syncthreads();
    l = redl[0] + redl[1] + redl[2] + redl[3];

    // phase B: o_d partial over this chunk's quarter
    const int d = lane, part = w;
    float o = 0.f;
    #pragma unroll 8
    for (int i = 0; i < 64; ++i) {
        int jj = c * 256 + part * 64 + i;
        int jjc = (jj < NTOT) ? jj : (NTOT - 1);
        o = fmaf(ps[part * 64 + i], bf2f(vb[((size_t)bh * NTOT + jjc) * 64 + d]), o);
    }
    so[part][d] = o;
    __syncthreads();
    if (t < 64) {
        float O = so[0][t] + so[1][t] + so[2][t] + so[3][t];
        int pi = bh * NCHUNK + c;
        cls_o[(size_t)pi * 64 + t] = O;
        if (t == 0) { cls_m[pi] = mx; cls_l[pi] = l; }
    }
}

// cls stage 2: merge 13 partials per bh, write bf16 row n=0.
__global__ __launch_bounds__(64) void attn_cls_merge_kernel(
    const float* __restrict__ cls_m, const float* __restrict__ cls_l,
    const float* __restrict__ cls_o, u16* __restrict__ attn)
{
    const int bh = blockIdx.x, lane = threadIdx.x;
    float M = -INFINITY;
    #pragma unroll
    for (int p = 0; p < NCHUNK; ++p) M = fmaxf(M, cls_m[bh * NCHUNK + p]);
    float L = 0.f, O = 0.f;
    #pragma unroll
    for (int p = 0; p < NCHUNK; ++p) {
        float al = __expf(cls_m[bh * NCHUNK + p] - M);
        L += cls_l[bh * NCHUNK + p] * al;
        O += cls_o[(size_t)(bh * NCHUNK + p) * 64 + lane] * al;
    }
    const int b = bh >> 3, h = bh & 7;
    attn[(size_t)b * NTOT * 512 + h * 64 + lane] = f2bf(O / L);
}

// ---------------------------------------------------------------------------
extern "C" void kernel_launch(void* const* d_in, const int* in_sizes, int n_in,
                              void* d_out, int out_size, void* d_ws, size_t ws_size,
                              hipStream_t stream) {
    const float* x    = (const float*)d_in[0];
    const float* wqkv = (const float*)d_in[1];
    const float* wout = (const float*)d_in[2];
    const float* bout = (const float*)d_in[3];

    u16* p = (u16*)d_ws;
    u16* xbf   = p;                    p += (size_t)MROWS * 512;  // reused as attn
    u16* attn  = xbf;                  // safe: xbf consumed by qkv gemm before attn writes
    u16* wqkvT = p;                    p += (size_t)1536 * 512;
    u16* woutT = p;                    p += (size_t)512 * 512;
    u16* qbuf  = p;                    p += QSZ_;
    u16* kbuf  = p;                    p += QSZ_;
    u16* vbuf  = p;                    p += QSZ_;
    float* clsws = (float*)p;
    float* cls_m = clsws;                       // [32*13]
    float* cls_l = clsws + BH_ * NCHUNK;        // [32*13]
    float* cls_o = clsws + 2 * BH_ * NCHUNK;    // [32*13][64]
    float* outp  = (float*)d_out;

    // input conversions
    convert_x_kernel<<<6274, 256, 0, stream>>>(x, xbf);
    transpose_bf16_kernel<<<dim3(48, 16), 256, 0, stream>>>(wqkv, wqkvT, 512, 1536);
    transpose_bf16_kernel<<<dim3(16, 16), 256, 0, stream>>>(wout, woutT, 512, 512);
    // qkv = x @ W_qkv (bf16 MFMA, BK=64 dbuf), epilogue -> q/k/v
    gemm_bf16_mfma<0><<<dim3(12, 99), 256, 0, stream>>>(
        xbf, wqkvT, qbuf, kbuf, vbuf, nullptr, nullptr);
    // attention: group-resident local attn (K/V^T staged in LDS once)
    attn_group_kernel<<<512, 512, 0, stream>>>(qbuf, kbuf, vbuf, attn);
    attn_cls_partial_kernel<<<dim3(NCHUNK, 32), 256, 0, stream>>>(
        qbuf, kbuf, vbuf, cls_m, cls_l, cls_o);
    attn_cls_merge_kernel<<<32, 64, 0, stream>>>(cls_m, cls_l, cls_o, attn);
    // out = attn @ W_out + b_out (bf16 MFMA, BK=64 dbuf)
    gemm_bf16_mfma<1><<<dim3(4, 99), 256, 0, stream>>>(
        attn, woutT, nullptr, nullptr, nullptr, outp, bout);
}

// Round 10
// 199.122 us; speedup vs baseline: 1.4178x; 1.0348x over previous
//
#include <hip/hip_runtime.h>
#include <math.h>

// (B, F, NP, DIM, H, DH) = (4, 16, 196, 512, 8, 64)
#define B_   4
#define F_   16
#define NP_  196
#define DIM_ 512
#define H_   8
#define DH_  64
#define NTOT 3137            // 1 + F*NP
#define BH_  32              // B*H
#define MROWS 12548          // B*NTOT
#define QSZ_ ((size_t)BH_ * NTOT * DH_)   // elements per q/k/v buffer
#define PSTRIDE 232          // P LDS row stride (u16): 16B-aligned, read-conflict-free
#define KSTRIDE 72           // K LDS row stride (u16)
#define VSTRIDE 232          // V^T LDS row stride (u16)
#define NGF 512              // BH_*16 cls partials

typedef unsigned short u16;
typedef __attribute__((ext_vector_type(8))) short    bf16x8;
typedef __attribute__((ext_vector_type(8))) unsigned short u16x8;
typedef __attribute__((ext_vector_type(4))) unsigned short u16x4;
typedef __attribute__((ext_vector_type(4))) float    f32x4;

__device__ __forceinline__ u16 f2bf(float f) {
    unsigned int u = __float_as_uint(f);
    unsigned int r = (u + 0x7FFFu + ((u >> 16) & 1u)) >> 16;
    return (u16)r;
}
__device__ __forceinline__ float bf2f(u16 u) {
    return __uint_as_float(((unsigned int)u) << 16);
}

// async global->LDS, 16B per lane. LDS dest must be wave-uniform base + lane*16.
__device__ __forceinline__ void gl2lds16(const u16* g, u16* l) {
    __builtin_amdgcn_global_load_lds(
        (const __attribute__((address_space(1))) unsigned int*)(g),
        (__attribute__((address_space(3))) unsigned int*)(l),
        16, 0, 0);
}

// ---------------------------------------------------------------------------
// prep: fused convert_x + transpose(wqkv) + transpose(wout).
// Block-uniform branch on blockIdx.x -> __syncthreads inside branches is safe.
// blocks [0,6274): convert x (fp32 MROWS x 512 -> bf16, one float4/thread)
// blocks [6274,7042): transpose wqkv 512x1536 -> 1536x512 bf16
// blocks [7042,7298): transpose wout 512x512 -> 512x512 bf16
// ---------------------------------------------------------------------------
__global__ __launch_bounds__(256) void prep_kernel(
    const float* __restrict__ x, u16* __restrict__ xbf,
    const float* __restrict__ wqkv, u16* __restrict__ wqkvT,
    const float* __restrict__ wout, u16* __restrict__ woutT)
{
    __shared__ float t[32][33];
    const int blk = blockIdx.x, tid = threadIdx.x;

    if (blk < 6274) {
        int idx = blk * 256 + tid;
        float4 v = ((const float4*)x)[idx];
        u16x4 p = { f2bf(v.x), f2bf(v.y), f2bf(v.z), f2bf(v.w) };
        *(u16x4*)(&xbf[(size_t)idx * 4]) = p;
        return;
    }
    const float* src; u16* dst; int R, C, bx, by;
    if (blk < 7042) {
        int bb = blk - 6274;  src = wqkv; dst = wqkvT; R = 512; C = 1536;
        bx = bb % 48; by = bb / 48;
    } else {
        int bb = blk - 7042;  src = wout; dst = woutT; R = 512; C = 512;
        bx = bb % 16; by = bb / 16;
    }
    const int tx = tid & 31, ty = tid >> 5;
    const int c0 = bx * 32, r0 = by * 32;
    #pragma unroll
    for (int i = 0; i < 4; ++i) {
        int r = ty + i * 8;
        t[r][tx] = src[(size_t)(r0 + r) * C + c0 + tx];
    }
    __syncthreads();
    #pragma unroll
    for (int i = 0; i < 4; ++i) {
        int cc = ty + i * 8;
        dst[(size_t)(c0 + cc) * R + r0 + tx] = f2bf(t[tx][cc]);
    }
}

// ---------------------------------------------------------------------------
// bf16 MFMA GEMM (round-9 verified: MODE0 = 65.7us):
//   C = A(MROWS x 512) * BT^T, 128x128 tile, BK=64, dbuf LDS, 4 waves 2x2.
// MODE 0: qkv epilogue -> bf16 q (x0.125) / k / v [bh][n][64]
// MODE 1: out epilogue (+bias, fp32 row-major)
// ---------------------------------------------------------------------------
template<int MODE>
__global__ __launch_bounds__(256, 2) void gemm_bf16_mfma(
    const u16* __restrict__ A, const u16* __restrict__ BT,
    u16* __restrict__ Cq, u16* __restrict__ Ck, u16* __restrict__ Cv,
    float* __restrict__ Cout, const float* __restrict__ bias)
{
    __shared__ alignas(16) u16 Asm[2][16 * 512];   // 2 x 16 KB
    __shared__ alignas(16) u16 Bsm[2][16 * 512];   // 2 x 16 KB

    const int tid  = threadIdx.x;
    const int wave = tid >> 6, lane = tid & 63;
    const int wr = wave >> 1, wc = wave & 1;
    const int lm = lane & 15, lq = lane >> 4;

    // bijective XCD swizzle (m204)
    constexpr int NX  = (MODE == 0) ? 12 : 4;
    constexpr int NWG = NX * 99;
    constexpr int SQ  = NWG / 8, SR = NWG % 8;
    const int orig = blockIdx.y * NX + blockIdx.x;
    const int xcd = orig & 7, loc = orig >> 3;
    const int wgid = (xcd < SR ? xcd * (SQ + 1) : SR * (SQ + 1) + (xcd - SR) * SQ) + loc;
    const int row0 = (wgid / NX) * 128;
    const int col0 = (wgid % NX) * 128;

    const u16* ApS[4]; const u16* BpS[4]; int ldsOff[4];
    #pragma unroll
    for (int i = 0; i < 4; ++i) {
        int slab = wave * 4 + i;
        int s = slab >> 1, kh = slab & 1;
        int ar = row0 + s * 16 + lm; if (ar >= MROWS) ar = MROWS - 1;
        int br = col0 + s * 16 + lm;
        ApS[i]   = A  + (size_t)ar * 512 + kh * 32 + lq * 8;
        BpS[i]   = BT + (size_t)br * 512 + kh * 32 + lq * 8;
        ldsOff[i] = slab * 512 + lane * 8;
    }

    auto stage = [&](int T, int BUF) {
        const int kn = T * 64;
        #pragma unroll
        for (int i = 0; i < 4; ++i) {
            gl2lds16(ApS[i] + kn, &Asm[BUF][ldsOff[i]]);
            gl2lds16(BpS[i] + kn, &Bsm[BUF][ldsOff[i]]);
        }
    };

    f32x4 acc[4][4];
    #pragma unroll
    for (int i = 0; i < 4; ++i)
        #pragma unroll
        for (int j = 0; j < 4; ++j) acc[i][j] = (f32x4){0.f, 0.f, 0.f, 0.f};

    stage(0, 0);
    __syncthreads();

    #pragma unroll
    for (int t = 0; t < 8; ++t) {
        const int cur = t & 1;
        if (t + 1 < 8) stage(t + 1, cur ^ 1);
        #pragma unroll
        for (int kh = 0; kh < 2; ++kh) {
            bf16x8 af[4], bfr[4];
            #pragma unroll
            for (int mi = 0; mi < 4; ++mi)
                af[mi] = *(const bf16x8*)(&Asm[cur][((wr * 4 + mi) * 2 + kh) * 512 + lane * 8]);
            #pragma unroll
            for (int ni = 0; ni < 4; ++ni)
                bfr[ni] = *(const bf16x8*)(&Bsm[cur][((wc * 4 + ni) * 2 + kh) * 512 + lane * 8]);
            #pragma unroll
            for (int mi = 0; mi < 4; ++mi)
                #pragma unroll
                for (int ni = 0; ni < 4; ++ni)
                    acc[mi][ni] = __builtin_amdgcn_mfma_f32_16x16x32_bf16(
                        af[mi], bfr[ni], acc[mi][ni], 0, 0, 0);
        }
        __syncthreads();
    }

    if (MODE == 0) {
        const int t3 = col0 >> 9;          // uniform per block
        #pragma unroll
        for (int mi = 0; mi < 4; ++mi) {
            #pragma unroll
            for (int r = 0; r < 4; ++r) {
                int gr = row0 + wr * 64 + mi * 16 + lq * 4 + r;
                if (gr >= MROWS) continue;
                int b = gr / NTOT;
                int n = gr - b * NTOT;
                #pragma unroll
                for (int ni = 0; ni < 4; ++ni) {
                    int gc = col0 + wc * 64 + ni * 16 + lm;
                    int rem = gc & 511;
                    int h = rem >> 6, d = rem & 63;
                    size_t tok = (size_t)(b * H_ + h) * NTOT + n;
                    float v = acc[mi][ni][r];
                    if (t3 == 0)      Cq[tok * 64 + d] = f2bf(v * 0.125f);
                    else if (t3 == 1) Ck[tok * 64 + d] = f2bf(v);
                    else              Cv[tok * 64 + d] = f2bf(v);
                }
            }
        }
    } else {
        float bb[4];
        #pragma unroll
        for (int ni = 0; ni < 4; ++ni)
            bb[ni] = bias[col0 + wc * 64 + ni * 16 + lm];
        #pragma unroll
        for (int mi = 0; mi < 4; ++mi) {
            #pragma unroll
            for (int r = 0; r < 4; ++r) {
                int gr = row0 + wr * 64 + mi * 16 + lq * 4 + r;
                if (gr >= MROWS) continue;
                #pragma unroll
                for (int ni = 0; ni < 4; ++ni) {
                    int gc = col0 + wc * 64 + ni * 16 + lm;
                    Cout[(size_t)gr * 512 + gc] = acc[mi][ni][r] + bb[ni];
                }
            }
        }
    }
}

// ---------------------------------------------------------------------------
// group-resident local attention + fused cls partial (round-10).
// One block per (bh,f): 512 blocks x 512 threads (8 waves).
// Stage K (197 rows -> 208, stride 72) and V^T (64 x 224, stride 232) once.
// NEW: cls partial computed here from the SAME staged K/V^T -- block (bh,f)
// covers exactly the kv rows {cls iff f==0} u {patch rows f*196+1..+196};
// writes (m,l,o[64]) per gf; merge kernel combines 16 partials per bh.
// Then 13 mt q-tiles over 8 waves, per-wave math verbatim from r9-verified.
// LDS: K 29.9K + V 29.7K + P 59.4K + cls scratch ~3.2K = 122.3KB, 1 block/CU.
// ---------------------------------------------------------------------------
__global__ __launch_bounds__(512) void attn_group_kernel(
    const u16* __restrict__ qb, const u16* __restrict__ kb,
    const u16* __restrict__ vb, u16* __restrict__ attn,
    float* __restrict__ cls_m, float* __restrict__ cls_l,
    float* __restrict__ cls_o)
{
    __shared__ alignas(16) u16 Ksm[208 * KSTRIDE];
    __shared__ alignas(16) u16 Vsm[64 * VSTRIDE];
    __shared__ alignas(16) u16 Pbuf[8 * 16 * PSTRIDE];
    __shared__ float qs[64];
    __shared__ float ps[208];
    __shared__ float redm[8], redl[8];
    __shared__ float so[8][64];

    const int tid  = threadIdx.x;
    const int wave = tid >> 6, lane = tid & 63;
    const int lm = lane & 15, lq = lane >> 4;
    const int gf = blockIdx.x;            // bh*16 + f
    const int f  = gf & 15;
    const int bh = gf >> 4;
    const int b = bh >> 3, h = bh & 7;
    const size_t kbase = (size_t)bh * NTOT;

    // ---- stage q row 0 (cls query, pre-scaled x0.125 in qbuf) ----
    if (tid < 64) qs[tid] = bf2f(qb[kbase * 64 + tid]);
    // ---- stage K: idx = (j, c); j = kv row 0..207, c = 16B chunk 0..7 ----
    for (int idx = tid; idx < 208 * 8; idx += 512) {
        int j = idx >> 3, c = idx & 7;
        u16x8 v8 = {0, 0, 0, 0, 0, 0, 0, 0};
        if (j < 197) {
            int n = (j == 0) ? 0 : (f * NP_ + j);      // 1 + f*196 + (j-1)
            v8 = *(const u16x8*)(kb + (kbase + n) * 64 + c * 8);
        }
        *(u16x8*)(&Ksm[j * KSTRIDE + c * 8]) = v8;
    }
    // ---- stage V transposed: idx = c*224 + j; c = d-chunk 0..7, j = kv ----
    for (int idx = tid; idx < 8 * 224; idx += 512) {
        int c = idx / 224, j = idx - c * 224;
        u16x8 v8 = {0, 0, 0, 0, 0, 0, 0, 0};
        if (j < 197) {
            int n = (j == 0) ? 0 : (f * NP_ + j);
            v8 = *(const u16x8*)(vb + (kbase + n) * 64 + c * 8);
        }
        #pragma unroll
        for (int e = 0; e < 8; ++e)
            Vsm[(c * 8 + e) * VSTRIDE + j] = v8[e];
    }
    __syncthreads();

    // ================= fused cls partial (all from LDS) =================
    // phase A: thread j scores q0 . K[j]; j==0 (cls) counted only in f==0
    float sj = -INFINITY;
    if (tid < 208) {
        const bool valid = (tid < 197) && (tid > 0 || f == 0);
        if (valid) {
            const u16* kr = &Ksm[tid * KSTRIDE];
            float s0 = 0.f, s1 = 0.f, s2 = 0.f, s3 = 0.f;
            #pragma unroll
            for (int i = 0; i < 8; ++i) {
                u16x8 k8 = *(const u16x8*)(kr + i * 8);
                const float* qp = qs + i * 8;
                s0 = fmaf(qp[0], bf2f(k8[0]), s0);
                s1 = fmaf(qp[1], bf2f(k8[1]), s1);
                s2 = fmaf(qp[2], bf2f(k8[2]), s2);
                s3 = fmaf(qp[3], bf2f(k8[3]), s3);
                s0 = fmaf(qp[4], bf2f(k8[4]), s0);
                s1 = fmaf(qp[5], bf2f(k8[5]), s1);
                s2 = fmaf(qp[6], bf2f(k8[6]), s2);
                s3 = fmaf(qp[7], bf2f(k8[7]), s3);
            }
            sj = (s0 + s1) + (s2 + s3);
        }
    }
    float mx = sj;
    #pragma unroll
    for (int off = 1; off < 64; off <<= 1) mx = fmaxf(mx, __shfl_xor(mx, off, 64));
    if (lane == 0) redm[wave] = mx;
    __syncthreads();
    mx = fmaxf(fmaxf(fmaxf(redm[0], redm[1]), fmaxf(redm[2], redm[3])),
               fmaxf(fmaxf(redm[4], redm[5]), fmaxf(redm[6], redm[7])));
    float pv = __expf(sj - mx);                 // -inf -> 0 for invalid/masked
    float lsum = pv;
    #pragma unroll
    for (int off = 1; off < 64; off <<= 1) lsum += __shfl_xor(lsum, off, 64);
    if (lane == 0) redl[wave] = lsum;
    if (tid < 208) ps[tid] = pv;
    __syncthreads();
    lsum = ((redl[0] + redl[1]) + (redl[2] + redl[3]))
         + ((redl[4] + redl[5]) + (redl[6] + redl[7]));
    // phase B: part = wave (8 x 26 rows), d = lane; V^T rows are d-major
    {
        const int d = lane, part = wave;
        float o = 0.f;
        #pragma unroll
        for (int i = 0; i < 26; ++i) {
            int j = part * 26 + i;
            o = fmaf(ps[j], bf2f(Vsm[d * VSTRIDE + j]), o);
        }
        so[part][d] = o;
    }
    __syncthreads();
    if (tid < 64) {
        float O = ((so[0][tid] + so[1][tid]) + (so[2][tid] + so[3][tid]))
                + ((so[4][tid] + so[5][tid]) + (so[6][tid] + so[7][tid]));
        cls_o[(size_t)gf * 64 + tid] = O;
        if (tid == 0) { cls_m[gf] = mx; cls_l[gf] = lsum; }
    }
    // ====================================================================

    u16* P = Pbuf + wave * 16 * PSTRIDE;
    {   // zero P cols 208..223 once per wave (A-frag reads cover up to 224)
        u16x4 z4 = {0, 0, 0, 0};
        *(u16x4*)(P + lm * PSTRIDE + 208 + lq * 4) = z4;
    }

    for (int mt = wave; mt < 13; mt += 8) {
        const int rq = min(mt * 16 + lm, 195);
        const u16* qrow = qb + (kbase + (1 + f * NP_ + rq)) * 64;
        bf16x8 qf0 = *(const bf16x8*)(qrow + lq * 8);
        bf16x8 qf1 = *(const bf16x8*)(qrow + 32 + lq * 8);

        // S = Q K^T over 13 kv tiles of 16 (kv j = nt*16 + lm; j==0 is cls)
        f32x4 S[13];
        #pragma unroll
        for (int nt = 0; nt < 13; ++nt) {
            const u16* krow = &Ksm[(nt * 16 + lm) * KSTRIDE];
            bf16x8 kf0 = *(const bf16x8*)(krow + lq * 8);
            bf16x8 kf1 = *(const bf16x8*)(krow + 32 + lq * 8);
            f32x4 z = (f32x4){0.f, 0.f, 0.f, 0.f};
            z = __builtin_amdgcn_mfma_f32_16x16x32_bf16(qf0, kf0, z, 0, 0, 0);
            z = __builtin_amdgcn_mfma_f32_16x16x32_bf16(qf1, kf1, z, 0, 0, 0);
            S[nt] = z;
        }

        #pragma unroll
        for (int nt = 0; nt < 13; ++nt)
            if (nt * 16 + lm >= 197) {
                S[nt][0] = -INFINITY; S[nt][1] = -INFINITY;
                S[nt][2] = -INFINITY; S[nt][3] = -INFINITY;
            }

        // single-pass softmax; row = lq*4 + r, cols across the 16-lane group
        float invl[4];
        #pragma unroll
        for (int r = 0; r < 4; ++r) {
            float rmx = -INFINITY;
            #pragma unroll
            for (int nt = 0; nt < 13; ++nt) rmx = fmaxf(rmx, S[nt][r]);
            rmx = fmaxf(rmx, __shfl_xor(rmx, 1, 64));
            rmx = fmaxf(rmx, __shfl_xor(rmx, 2, 64));
            rmx = fmaxf(rmx, __shfl_xor(rmx, 4, 64));
            rmx = fmaxf(rmx, __shfl_xor(rmx, 8, 64));
            float sum = 0.f;
            #pragma unroll
            for (int nt = 0; nt < 13; ++nt) {
                float p = __expf(S[nt][r] - rmx);   // exp(-inf)=0 for masked cols
                S[nt][r] = p;
                sum += p;
            }
            sum += __shfl_xor(sum, 1, 64);
            sum += __shfl_xor(sum, 2, 64);
            sum += __shfl_xor(sum, 4, 64);
            sum += __shfl_xor(sum, 8, 64);
            invl[r] = 1.f / sum;
        }

        // P -> LDS (C-layout scatter), then re-read as A-fragments
        #pragma unroll
        for (int nt = 0; nt < 13; ++nt) {
            int col = nt * 16 + lm;
            #pragma unroll
            for (int r = 0; r < 4; ++r)
                P[(lq * 4 + r) * PSTRIDE + col] = f2bf(S[nt][r]);
        }

        // O = P * V  (B operand from LDS V^T, kv-contiguous rows)
        f32x4 O[4];
        #pragma unroll
        for (int nd = 0; nd < 4; ++nd) O[nd] = (f32x4){0.f, 0.f, 0.f, 0.f};
        #pragma unroll
        for (int ks = 0; ks < 7; ++ks) {
            bf16x8 pf = *(const bf16x8*)(P + lm * PSTRIDE + ks * 32 + lq * 8);
            #pragma unroll
            for (int nd = 0; nd < 4; ++nd) {
                bf16x8 vf = *(const bf16x8*)(&Vsm[(nd * 16 + lm) * VSTRIDE + ks * 32 + lq * 8]);
                O[nd] = __builtin_amdgcn_mfma_f32_16x16x32_bf16(pf, vf, O[nd], 0, 0, 0);
            }
        }

        #pragma unroll
        for (int r = 0; r < 4; ++r) {
            int rql = mt * 16 + lq * 4 + r;
            if (rql >= 196) continue;
            int n = 1 + f * NP_ + rql;
            u16* dst = attn + ((size_t)b * NTOT + n) * 512 + h * 64;
            float s = invl[r];
            #pragma unroll
            for (int nd = 0; nd < 4; ++nd)
                dst[nd * 16 + lm] = f2bf(O[nd][r] * s);
        }
    }
}

// cls stage 2: merge 16 f-partials per bh, write bf16 row n=0.
__global__ __launch_bounds__(64) void attn_cls_merge_kernel(
    const float* __restrict__ cls_m, const float* __restrict__ cls_l,
    const float* __restrict__ cls_o, u16* __restrict__ attn)
{
    const int bh = blockIdx.x, lane = threadIdx.x;
    float M = -INFINITY;
    #pragma unroll
    for (int p = 0; p < 16; ++p) M = fmaxf(M, cls_m[bh * 16 + p]);
    float L = 0.f, O = 0.f;
    #pragma unroll
    for (int p = 0; p < 16; ++p) {
        float al = __expf(cls_m[bh * 16 + p] - M);
        L += cls_l[bh * 16 + p] * al;
        O += cls_o[(size_t)(bh * 16 + p) * 64 + lane] * al;
    }
    const int b = bh >> 3, h = bh & 7;
    attn[(size_t)b * NTOT * 512 + h * 64 + lane] = f2bf(O / L);
}

// ---------------------------------------------------------------------------
extern "C" void kernel_launch(void* const* d_in, const int* in_sizes, int n_in,
                              void* d_out, int out_size, void* d_ws, size_t ws_size,
                              hipStream_t stream) {
    const float* x    = (const float*)d_in[0];
    const float* wqkv = (const float*)d_in[1];
    const float* wout = (const float*)d_in[2];
    const float* bout = (const float*)d_in[3];

    u16* p = (u16*)d_ws;
    u16* xbf   = p;                    p += (size_t)MROWS * 512;  // reused as attn
    u16* attn  = xbf;                  // safe: xbf consumed by qkv gemm before attn writes
    u16* wqkvT = p;                    p += (size_t)1536 * 512;
    u16* woutT = p;                    p += (size_t)512 * 512;
    u16* qbuf  = p;                    p += QSZ_;
    u16* kbuf  = p;                    p += QSZ_;
    u16* vbuf  = p;                    p += QSZ_;
    float* clsws = (float*)p;
    float* cls_m = clsws;                       // [512]
    float* cls_l = clsws + NGF;                 // [512]
    float* cls_o = clsws + 2 * NGF;             // [512][64]
    float* outp  = (float*)d_out;

    // fused input conversions (convert_x + both weight transposes)
    prep_kernel<<<7298, 256, 0, stream>>>(x, xbf, wqkv, wqkvT, wout, woutT);
    // qkv = x @ W_qkv (bf16 MFMA, BK=64 dbuf), epilogue -> q/k/v
    gemm_bf16_mfma<0><<<dim3(12, 99), 256, 0, stream>>>(
        xbf, wqkvT, qbuf, kbuf, vbuf, nullptr, nullptr);
    // attention: group-resident local attn + fused cls partial
    attn_group_kernel<<<512, 512, 0, stream>>>(
        qbuf, kbuf, vbuf, attn, cls_m, cls_l, cls_o);
    attn_cls_merge_kernel<<<32, 64, 0, stream>>>(cls_m, cls_l, cls_o, attn);
    // out = attn @ W_out + b_out (bf16 MFMA, BK=64 dbuf)
    gemm_bf16_mfma<1><<<dim3(4, 99), 256, 0, stream>>>(
        attn, woutT, nullptr, nullptr, nullptr, outp, bout);
}

// Round 11
// 183.087 us; speedup vs baseline: 1.5419x; 1.0876x over previous
//
#include <hip/hip_runtime.h>
#include <math.h>

// (B, F, NP, DIM, H, DH) = (4, 16, 196, 512, 8, 64)
#define B_   4
#define F_   16
#define NP_  196
#define DIM_ 512
#define H_   8
#define DH_  64
#define NTOT 3137            // 1 + F*NP
#define BH_  32              // B*H
#define MROWS 12548          // B*NTOT
#define QSZ_ ((size_t)BH_ * NTOT * DH_)   // elements per q/k/v buffer
#define PSTRIDE 232          // P LDS row stride (u16): 16B-aligned, read-conflict-free
#define KSTRIDE 72           // K LDS row stride (u16)
#define VSTRIDE 232          // V^T LDS row stride (u16)
#define NGF 512              // BH_*16 cls partials

typedef unsigned short u16;
typedef __attribute__((ext_vector_type(8))) short    bf16x8;
typedef __attribute__((ext_vector_type(8))) unsigned short u16x8;
typedef __attribute__((ext_vector_type(4))) unsigned short u16x4;
typedef __attribute__((ext_vector_type(4))) float    f32x4;

__device__ __forceinline__ u16 f2bf(float f) {
    unsigned int u = __float_as_uint(f);
    unsigned int r = (u + 0x7FFFu + ((u >> 16) & 1u)) >> 16;
    return (u16)r;
}
__device__ __forceinline__ float bf2f(u16 u) {
    return __uint_as_float(((unsigned int)u) << 16);
}

// async global->LDS, 16B per lane. LDS dest must be wave-uniform base + lane*16.
__device__ __forceinline__ void gl2lds16(const u16* g, u16* l) {
    __builtin_amdgcn_global_load_lds(
        (const __attribute__((address_space(1))) unsigned int*)(g),
        (__attribute__((address_space(3))) unsigned int*)(l),
        16, 0, 0);
}

// ---------------------------------------------------------------------------
// prep: fused convert_x + transpose(wqkv) + transpose(wout).
// ---------------------------------------------------------------------------
__global__ __launch_bounds__(256) void prep_kernel(
    const float* __restrict__ x, u16* __restrict__ xbf,
    const float* __restrict__ wqkv, u16* __restrict__ wqkvT,
    const float* __restrict__ wout, u16* __restrict__ woutT)
{
    __shared__ float t[32][33];
    const int blk = blockIdx.x, tid = threadIdx.x;

    if (blk < 6274) {
        int idx = blk * 256 + tid;
        float4 v = ((const float4*)x)[idx];
        u16x4 p = { f2bf(v.x), f2bf(v.y), f2bf(v.z), f2bf(v.w) };
        *(u16x4*)(&xbf[(size_t)idx * 4]) = p;
        return;
    }
    const float* src; u16* dst; int R, C, bx, by;
    if (blk < 7042) {
        int bb = blk - 6274;  src = wqkv; dst = wqkvT; R = 512; C = 1536;
        bx = bb % 48; by = bb / 48;
    } else {
        int bb = blk - 7042;  src = wout; dst = woutT; R = 512; C = 512;
        bx = bb % 16; by = bb / 16;
    }
    const int tx = tid & 31, ty = tid >> 5;
    const int c0 = bx * 32, r0 = by * 32;
    #pragma unroll
    for (int i = 0; i < 4; ++i) {
        int r = ty + i * 8;
        t[r][tx] = src[(size_t)(r0 + r) * C + c0 + tx];
    }
    __syncthreads();
    #pragma unroll
    for (int i = 0; i < 4; ++i) {
        int cc = ty + i * 8;
        dst[(size_t)(c0 + cc) * R + r0 + tx] = f2bf(t[tx][cc]);
    }
}

// ---------------------------------------------------------------------------
// bf16 MFMA GEMM, round-11: K-loop verbatim from r10 (verified); epilogue
// rerouted through LDS -> full 16B coalesced global stores.
// Rationale: r9's only real GEMM win was removing a scattered store stream;
// both modes still issued 64 scatter-store instrs/thread (4 rows x 32B per
// instr, half-sector). Now: acc -> LDS (scatter, cheap) -> re-read row-major
// -> 8 x 16B stores/thread, 128-512B contiguous per wave. Two 64-row passes
// reuse the 64KB stage LDS (dead after the K-loop), occupancy unchanged.
// MODE 0: qkv epilogue -> bf16 q (x0.125) / k / v [bh][n][64]
// MODE 1: out epilogue (+bias, fp32 row-major)
// ---------------------------------------------------------------------------
template<int MODE>
__global__ __launch_bounds__(256, 2) void gemm_bf16_mfma(
    const u16* __restrict__ A, const u16* __restrict__ BT,
    u16* __restrict__ Cq, u16* __restrict__ Ck, u16* __restrict__ Cv,
    float* __restrict__ Cout, const float* __restrict__ bias)
{
    __shared__ alignas(16) u16 SM[32768];          // 64 KB: stage bufs / epilogue
    u16* const Ab0 = SM;            u16* const Ab1 = SM + 8192;
    u16* const Bb0 = SM + 16384;    u16* const Bb1 = SM + 24576;
    u16* const Abuf[2] = { Ab0, Ab1 };
    u16* const Bbuf[2] = { Bb0, Bb1 };

    const int tid  = threadIdx.x;
    const int wave = tid >> 6, lane = tid & 63;
    const int wr = wave >> 1, wc = wave & 1;
    const int lm = lane & 15, lq = lane >> 4;

    // bijective XCD swizzle (m204)
    constexpr int NX  = (MODE == 0) ? 12 : 4;
    constexpr int NWG = NX * 99;
    constexpr int SQ  = NWG / 8, SR = NWG % 8;
    const int orig = blockIdx.y * NX + blockIdx.x;
    const int xcd = orig & 7, loc = orig >> 3;
    const int wgid = (xcd < SR ? xcd * (SQ + 1) : SR * (SQ + 1) + (xcd - SR) * SQ) + loc;
    const int row0 = (wgid / NX) * 128;
    const int col0 = (wgid % NX) * 128;

    const u16* ApS[4]; const u16* BpS[4]; int ldsOff[4];
    #pragma unroll
    for (int i = 0; i < 4; ++i) {
        int slab = wave * 4 + i;
        int s = slab >> 1, kh = slab & 1;
        int ar = row0 + s * 16 + lm; if (ar >= MROWS) ar = MROWS - 1;
        int br = col0 + s * 16 + lm;
        ApS[i]   = A  + (size_t)ar * 512 + kh * 32 + lq * 8;
        BpS[i]   = BT + (size_t)br * 512 + kh * 32 + lq * 8;
        ldsOff[i] = slab * 512 + lane * 8;
    }

    auto stage = [&](int T, int BUF) {
        const int kn = T * 64;
        #pragma unroll
        for (int i = 0; i < 4; ++i) {
            gl2lds16(ApS[i] + kn, Abuf[BUF] + ldsOff[i]);
            gl2lds16(BpS[i] + kn, Bbuf[BUF] + ldsOff[i]);
        }
    };

    f32x4 acc[4][4];
    #pragma unroll
    for (int i = 0; i < 4; ++i)
        #pragma unroll
        for (int j = 0; j < 4; ++j) acc[i][j] = (f32x4){0.f, 0.f, 0.f, 0.f};

    stage(0, 0);
    __syncthreads();

    #pragma unroll
    for (int t = 0; t < 8; ++t) {
        const int cur = t & 1;
        if (t + 1 < 8) stage(t + 1, cur ^ 1);
        #pragma unroll
        for (int kh = 0; kh < 2; ++kh) {
            bf16x8 af[4], bfr[4];
            #pragma unroll
            for (int mi = 0; mi < 4; ++mi)
                af[mi] = *(const bf16x8*)(Abuf[cur] + ((wr * 4 + mi) * 2 + kh) * 512 + lane * 8);
            #pragma unroll
            for (int ni = 0; ni < 4; ++ni)
                bfr[ni] = *(const bf16x8*)(Bbuf[cur] + ((wc * 4 + ni) * 2 + kh) * 512 + lane * 8);
            #pragma unroll
            for (int mi = 0; mi < 4; ++mi)
                #pragma unroll
                for (int ni = 0; ni < 4; ++ni)
                    acc[mi][ni] = __builtin_amdgcn_mfma_f32_16x16x32_bf16(
                        af[mi], bfr[ni], acc[mi][ni], 0, 0, 0);
        }
        __syncthreads();
    }

    // ---- epilogue via LDS: two 64-row passes, 16B coalesced stores ----
    if (MODE == 0) {
        u16* E16 = SM;                       // [64][136] u16, 17.4 KB
        const int t3 = col0 >> 9;            // 0=q 1=k 2=v (uniform per block)
        const int h0 = (col0 & 511) >> 6;    // head of cols [0,64)
        u16* const dst = (t3 == 0) ? Cq : ((t3 == 1) ? Ck : Cv);
        const float qs = (t3 == 0) ? 0.125f : 1.0f;
        #pragma unroll
        for (int pass = 0; pass < 2; ++pass) {
            if (wr == pass) {
                #pragma unroll
                for (int mi = 0; mi < 4; ++mi)
                    #pragma unroll
                    for (int r = 0; r < 4; ++r) {
                        int row = mi * 16 + lq * 4 + r;
                        #pragma unroll
                        for (int ni = 0; ni < 4; ++ni)
                            E16[row * 136 + wc * 64 + ni * 16 + lm] =
                                f2bf(acc[mi][ni][r] * qs);
                    }
            }
            __syncthreads();
            #pragma unroll
            for (int s = 0; s < 4; ++s) {
                int hr = (tid >> 4) + s * 16;      // 0..63
                int sg = tid & 15;                 // 16B segment (cols sg*8..+7)
                int gr = row0 + pass * 64 + hr;
                if (gr < MROWS) {
                    u16x8 v8 = *(const u16x8*)&E16[hr * 136 + sg * 8];
                    int b = gr / NTOT, n = gr - b * NTOT;
                    int h = h0 + (sg >> 3);
                    size_t tok = (size_t)(b * H_ + h) * NTOT + n;
                    *(u16x8*)&dst[tok * 64 + (sg & 7) * 8] = v8;
                }
            }
            __syncthreads();
        }
    } else {
        float* Ef = (float*)SM;              // [64][132] f32, 33.8 KB
        #pragma unroll
        for (int pass = 0; pass < 2; ++pass) {
            if (wr == pass) {
                #pragma unroll
                for (int mi = 0; mi < 4; ++mi)
                    #pragma unroll
                    for (int r = 0; r < 4; ++r) {
                        int row = mi * 16 + lq * 4 + r;
                        #pragma unroll
                        for (int ni = 0; ni < 4; ++ni)
                            Ef[row * 132 + wc * 64 + ni * 16 + lm] = acc[mi][ni][r];
                    }
            }
            __syncthreads();
            #pragma unroll
            for (int s = 0; s < 8; ++s) {
                int hr = (tid >> 5) + s * 8;       // 0..63
                int seg = tid & 31;                // float4 segment (cols seg*4..+3)
                int gr = row0 + pass * 64 + hr;
                if (gr < MROWS) {
                    float4 v = *(const float4*)&Ef[hr * 132 + seg * 4];
                    float4 bb = *(const float4*)&bias[col0 + seg * 4];
                    v.x += bb.x; v.y += bb.y; v.z += bb.z; v.w += bb.w;
                    *(float4*)&Cout[(size_t)gr * 512 + col0 + seg * 4] = v;
                }
            }
            __syncthreads();
        }
    }
}

// ---------------------------------------------------------------------------
// group-resident local attention + fused cls partial (r10-verified, verbatim).
// ---------------------------------------------------------------------------
__global__ __launch_bounds__(512) void attn_group_kernel(
    const u16* __restrict__ qb, const u16* __restrict__ kb,
    const u16* __restrict__ vb, u16* __restrict__ attn,
    float* __restrict__ cls_m, float* __restrict__ cls_l,
    float* __restrict__ cls_o)
{
    __shared__ alignas(16) u16 Ksm[208 * KSTRIDE];
    __shared__ alignas(16) u16 Vsm[64 * VSTRIDE];
    __shared__ alignas(16) u16 Pbuf[8 * 16 * PSTRIDE];
    __shared__ float qs[64];
    __shared__ float ps[208];
    __shared__ float redm[8], redl[8];
    __shared__ float so[8][64];

    const int tid  = threadIdx.x;
    const int wave = tid >> 6, lane = tid & 63;
    const int lm = lane & 15, lq = lane >> 4;
    const int gf = blockIdx.x;            // bh*16 + f
    const int f  = gf & 15;
    const int bh = gf >> 4;
    const int b = bh >> 3, h = bh & 7;
    const size_t kbase = (size_t)bh * NTOT;

    if (tid < 64) qs[tid] = bf2f(qb[kbase * 64 + tid]);
    for (int idx = tid; idx < 208 * 8; idx += 512) {
        int j = idx >> 3, c = idx & 7;
        u16x8 v8 = {0, 0, 0, 0, 0, 0, 0, 0};
        if (j < 197) {
            int n = (j == 0) ? 0 : (f * NP_ + j);      // 1 + f*196 + (j-1)
            v8 = *(const u16x8*)(kb + (kbase + n) * 64 + c * 8);
        }
        *(u16x8*)(&Ksm[j * KSTRIDE + c * 8]) = v8;
    }
    for (int idx = tid; idx < 8 * 224; idx += 512) {
        int c = idx / 224, j = idx - c * 224;
        u16x8 v8 = {0, 0, 0, 0, 0, 0, 0, 0};
        if (j < 197) {
            int n = (j == 0) ? 0 : (f * NP_ + j);
            v8 = *(const u16x8*)(vb + (kbase + n) * 64 + c * 8);
        }
        #pragma unroll
        for (int e = 0; e < 8; ++e)
            Vsm[(c * 8 + e) * VSTRIDE + j] = v8[e];
    }
    __syncthreads();

    // ================= fused cls partial (all from LDS) =================
    float sj = -INFINITY;
    if (tid < 208) {
        const bool valid = (tid < 197) && (tid > 0 || f == 0);
        if (valid) {
            const u16* kr = &Ksm[tid * KSTRIDE];
            float s0 = 0.f, s1 = 0.f, s2 = 0.f, s3 = 0.f;
            #pragma unroll
            for (int i = 0; i < 8; ++i) {
                u16x8 k8 = *(const u16x8*)(kr + i * 8);
                const float* qp = qs + i * 8;
                s0 = fmaf(qp[0], bf2f(k8[0]), s0);
                s1 = fmaf(qp[1], bf2f(k8[1]), s1);
                s2 = fmaf(qp[2], bf2f(k8[2]), s2);
                s3 = fmaf(qp[3], bf2f(k8[3]), s3);
                s0 = fmaf(qp[4], bf2f(k8[4]), s0);
                s1 = fmaf(qp[5], bf2f(k8[5]), s1);
                s2 = fmaf(qp[6], bf2f(k8[6]), s2);
                s3 = fmaf(qp[7], bf2f(k8[7]), s3);
            }
            sj = (s0 + s1) + (s2 + s3);
        }
    }
    float mx = sj;
    #pragma unroll
    for (int off = 1; off < 64; off <<= 1) mx = fmaxf(mx, __shfl_xor(mx, off, 64));
    if (lane == 0) redm[wave] = mx;
    __syncthreads();
    mx = fmaxf(fmaxf(fmaxf(redm[0], redm[1]), fmaxf(redm[2], redm[3])),
               fmaxf(fmaxf(redm[4], redm[5]), fmaxf(redm[6], redm[7])));
    float pv = __expf(sj - mx);
    float lsum = pv;
    #pragma unroll
    for (int off = 1; off < 64; off <<= 1) lsum += __shfl_xor(lsum, off, 64);
    if (lane == 0) redl[wave] = lsum;
    if (tid < 208) ps[tid] = pv;
    __syncthreads();
    lsum = ((redl[0] + redl[1]) + (redl[2] + redl[3]))
         + ((redl[4] + redl[5]) + (redl[6] + redl[7]));
    {
        const int d = lane, part = wave;
        float o = 0.f;
        #pragma unroll
        for (int i = 0; i < 26; ++i) {
            int j = part * 26 + i;
            o = fmaf(ps[j], bf2f(Vsm[d * VSTRIDE + j]), o);
        }
        so[part][d] = o;
    }
    __syncthreads();
    if (tid < 64) {
        float O = ((so[0][tid] + so[1][tid]) + (so[2][tid] + so[3][tid]))
                + ((so[4][tid] + so[5][tid]) + (so[6][tid] + so[7][tid]));
        cls_o[(size_t)gf * 64 + tid] = O;
        if (tid == 0) { cls_m[gf] = mx; cls_l[gf] = lsum; }
    }
    // ====================================================================

    u16* P = Pbuf + wave * 16 * PSTRIDE;
    {
        u16x4 z4 = {0, 0, 0, 0};
        *(u16x4*)(P + lm * PSTRIDE + 208 + lq * 4) = z4;
    }

    for (int mt = wave; mt < 13; mt += 8) {
        const int rq = min(mt * 16 + lm, 195);
        const u16* qrow = qb + (kbase + (1 + f * NP_ + rq)) * 64;
        bf16x8 qf0 = *(const bf16x8*)(qrow + lq * 8);
        bf16x8 qf1 = *(const bf16x8*)(qrow + 32 + lq * 8);

        f32x4 S[13];
        #pragma unroll
        for (int nt = 0; nt < 13; ++nt) {
            const u16* krow = &Ksm[(nt * 16 + lm) * KSTRIDE];
            bf16x8 kf0 = *(const bf16x8*)(krow + lq * 8);
            bf16x8 kf1 = *(const bf16x8*)(krow + 32 + lq * 8);
            f32x4 z = (f32x4){0.f, 0.f, 0.f, 0.f};
            z = __builtin_amdgcn_mfma_f32_16x16x32_bf16(qf0, kf0, z, 0, 0, 0);
            z = __builtin_amdgcn_mfma_f32_16x16x32_bf16(qf1, kf1, z, 0, 0, 0);
            S[nt] = z;
        }

        #pragma unroll
        for (int nt = 0; nt < 13; ++nt)
            if (nt * 16 + lm >= 197) {
                S[nt][0] = -INFINITY; S[nt][1] = -INFINITY;
                S[nt][2] = -INFINITY; S[nt][3] = -INFINITY;
            }

        float invl[4];
        #pragma unroll
        for (int r = 0; r < 4; ++r) {
            float rmx = -INFINITY;
            #pragma unroll
            for (int nt = 0; nt < 13; ++nt) rmx = fmaxf(rmx, S[nt][r]);
            rmx = fmaxf(rmx, __shfl_xor(rmx, 1, 64));
            rmx = fmaxf(rmx, __shfl_xor(rmx, 2, 64));
            rmx = fmaxf(rmx, __shfl_xor(rmx, 4, 64));
            rmx = fmaxf(rmx, __shfl_xor(rmx, 8, 64));
            float sum = 0.f;
            #pragma unroll
            for (int nt = 0; nt < 13; ++nt) {
                float p = __expf(S[nt][r] - rmx);
                S[nt][r] = p;
                sum += p;
            }
            sum += __shfl_xor(sum, 1, 64);
            sum += __shfl_xor(sum, 2, 64);
            sum += __shfl_xor(sum, 4, 64);
            sum += __shfl_xor(sum, 8, 64);
            invl[r] = 1.f / sum;
        }

        #pragma unroll
        for (int nt = 0; nt < 13; ++nt) {
            int col = nt * 16 + lm;
            #pragma unroll
            for (int r = 0; r < 4; ++r)
                P[(lq * 4 + r) * PSTRIDE + col] = f2bf(S[nt][r]);
        }

        f32x4 O[4];
        #pragma unroll
        for (int nd = 0; nd < 4; ++nd) O[nd] = (f32x4){0.f, 0.f, 0.f, 0.f};
        #pragma unroll
        for (int ks = 0; ks < 7; ++ks) {
            bf16x8 pf = *(const bf16x8*)(P + lm * PSTRIDE + ks * 32 + lq * 8);
            #pragma unroll
            for (int nd = 0; nd < 4; ++nd) {
                bf16x8 vf = *(const bf16x8*)(&Vsm[(nd * 16 + lm) * VSTRIDE + ks * 32 + lq * 8]);
                O[nd] = __builtin_amdgcn_mfma_f32_16x16x32_bf16(pf, vf, O[nd], 0, 0, 0);
            }
        }

        #pragma unroll
        for (int r = 0; r < 4; ++r) {
            int rql = mt * 16 + lq * 4 + r;
            if (rql >= 196) continue;
            int n = 1 + f * NP_ + rql;
            u16* dst = attn + ((size_t)b * NTOT + n) * 512 + h * 64;
            float s = invl[r];
            #pragma unroll
            for (int nd = 0; nd < 4; ++nd)
                dst[nd * 16 + lm] = f2bf(O[nd][r] * s);
        }
    }
}

// cls stage 2: merge 16 f-partials per bh, write bf16 row n=0.
__global__ __launch_bounds__(64) void attn_cls_merge_kernel(
    const float* __restrict__ cls_m, const float* __restrict__ cls_l,
    const float* __restrict__ cls_o, u16* __restrict__ attn)
{
    const int bh = blockIdx.x, lane = threadIdx.x;
    float M = -INFINITY;
    #pragma unroll
    for (int p = 0; p < 16; ++p) M = fmaxf(M, cls_m[bh * 16 + p]);
    float L = 0.f, O = 0.f;
    #pragma unroll
    for (int p = 0; p < 16; ++p) {
        float al = __expf(cls_m[bh * 16 + p] - M);
        L += cls_l[bh * 16 + p] * al;
        O += cls_o[(size_t)(bh * 16 + p) * 64 + lane] * al;
    }
    const int b = bh >> 3, h = bh & 7;
    attn[(size_t)b * NTOT * 512 + h * 64 + lane] = f2bf(O / L);
}

// ---------------------------------------------------------------------------
extern "C" void kernel_launch(void* const* d_in, const int* in_sizes, int n_in,
                              void* d_out, int out_size, void* d_ws, size_t ws_size,
                              hipStream_t stream) {
    const float* x    = (const float*)d_in[0];
    const float* wqkv = (const float*)d_in[1];
    const float* wout = (const float*)d_in[2];
    const float* bout = (const float*)d_in[3];

    u16* p = (u16*)d_ws;
    u16* xbf   = p;                    p += (size_t)MROWS * 512;  // reused as attn
    u16* attn  = xbf;                  // safe: xbf consumed by qkv gemm before attn writes
    u16* wqkvT = p;                    p += (size_t)1536 * 512;
    u16* woutT = p;                    p += (size_t)512 * 512;
    u16* qbuf  = p;                    p += QSZ_;
    u16* kbuf  = p;                    p += QSZ_;
    u16* vbuf  = p;                    p += QSZ_;
    float* clsws = (float*)p;
    float* cls_m = clsws;                       // [512]
    float* cls_l = clsws + NGF;                 // [512]
    float* cls_o = clsws + 2 * NGF;             // [512][64]
    float* outp  = (float*)d_out;

    // fused input conversions (convert_x + both weight transposes)
    prep_kernel<<<7298, 256, 0, stream>>>(x, xbf, wqkv, wqkvT, wout, woutT);
    // qkv = x @ W_qkv (bf16 MFMA, BK=64 dbuf, LDS-coalesced epilogue)
    gemm_bf16_mfma<0><<<dim3(12, 99), 256, 0, stream>>>(
        xbf, wqkvT, qbuf, kbuf, vbuf, nullptr, nullptr);
    // attention: group-resident local attn + fused cls partial
    attn_group_kernel<<<512, 512, 0, stream>>>(
        qbuf, kbuf, vbuf, attn, cls_m, cls_l, cls_o);
    attn_cls_merge_kernel<<<32, 64, 0, stream>>>(cls_m, cls_l, cls_o, attn);
    // out = attn @ W_out + b_out (bf16 MFMA, BK=64 dbuf, LDS-coalesced epilogue)
    gemm_bf16_mfma<1><<<dim3(4, 99), 256, 0, stream>>>(
        attn, woutT, nullptr, nullptr, nullptr, outp, bout);
}